// Round 2
// 1029.966 us; speedup vs baseline: 1.0730x; 1.0730x over previous
//
#include <hip/hip_runtime.h>

#define CDIM 64
#define COARSE_SHIFT 10          // 1024 rows per coarse bucket
#define CHUNK 8192
#define MAXB 256                 // >= max coarse buckets (200000>>10 = 196)

// ---------------- init: residual slots of d_out ----------------
__global__ void init_kernel(const float4* __restrict__ user_emb,
                            const float4* __restrict__ ent_emb,
                            float4* __restrict__ outUserRes,
                            float4* __restrict__ outNodeRes,
                            long nuC4, long neC4) {
    long i = (long)blockIdx.x * blockDim.x + threadIdx.x;
    if (i < nuC4) { float4 v = user_emb[i]; outUserRes[i] = v; outNodeRes[i] = v; }
    if (i < neC4) { outNodeRes[nuC4 + i] = ent_emb[i]; }
}

// ---------------- coarse histogram (LDS-staged) ----------------
__global__ void hist_coarse(const int* __restrict__ dst, int n,
                            int* __restrict__ cnt, int Bc) {
    __shared__ int h[MAXB];
    for (int i = threadIdx.x; i < MAXB; i += blockDim.x) h[i] = 0;
    __syncthreads();
    int stride = gridDim.x * blockDim.x;
    for (int e = blockIdx.x * blockDim.x + threadIdx.x; e < n; e += stride)
        atomicAdd(&h[dst[e] >> COARSE_SHIFT], 1);
    __syncthreads();
    for (int b = threadIdx.x; b < Bc; b += blockDim.x)
        if (h[b]) atomicAdd(&cnt[b], h[b]);
}

// ---------------- small exclusive scan (single WG, n<=256) ----------------
__global__ void scan_small(const int* __restrict__ cnt, int* __restrict__ start,
                           int* __restrict__ cursor, int n) {
    __shared__ int tmp[256];
    int x = threadIdx.x;
    int v = (x < n) ? cnt[x] : 0;
    tmp[x] = v; __syncthreads();
    for (int off = 1; off < 256; off <<= 1) {
        int t = (x >= off) ? tmp[x - off] : 0;
        __syncthreads();
        tmp[x] += t;
        __syncthreads();
    }
    if (x < n) { start[x] = tmp[x] - v; cursor[x] = tmp[x] - v; }
    if (x == n - 1) start[n] = tmp[x];
}

// ---------------- coarse binning, LDS-staged segment writes ----------------
// key = rowlocal<<22 | typ<<18 | src   (rowlocal<1024, typ<16, src<2^18)
__global__ void bin_pairs(const int* __restrict__ dst, const int* __restrict__ src,
                          const int* __restrict__ typ, int typeBias, int n,
                          int* __restrict__ cursor, int* __restrict__ stage) {
    __shared__ int h[MAXB];
    __shared__ int base[MAXB];
    int cs = blockIdx.x * CHUNK;
    int ce = min(cs + CHUNK, n);
    for (int i = threadIdx.x; i < MAXB; i += blockDim.x) h[i] = 0;
    __syncthreads();
    for (int e = cs + threadIdx.x; e < ce; e += blockDim.x)
        atomicAdd(&h[dst[e] >> COARSE_SHIFT], 1);
    __syncthreads();
    for (int b = threadIdx.x; b < MAXB; b += blockDim.x) {
        int c = h[b];
        base[b] = c ? atomicAdd(&cursor[b], c) : 0;
        h[b] = 0;
    }
    __syncthreads();
    for (int e = cs + threadIdx.x; e < ce; e += blockDim.x) {
        int d = dst[e];
        int b = d >> COARSE_SHIFT;
        int off = atomicAdd(&h[b], 1);
        stage[base[b] + off] = ((d & 1023) << 22) | ((typ[e] + typeBias) << 18) | src[e];
    }
}

// user variant: key = rowlocal<<22 | col (col<2^22), parallel val array
__global__ void bin_user(const int* __restrict__ row, const int* __restrict__ col,
                         const float* __restrict__ val, int n,
                         int* __restrict__ cursor,
                         int* __restrict__ stage, float* __restrict__ stageVal) {
    __shared__ int h[MAXB];
    __shared__ int base[MAXB];
    int cs = blockIdx.x * CHUNK;
    int ce = min(cs + CHUNK, n);
    for (int i = threadIdx.x; i < MAXB; i += blockDim.x) h[i] = 0;
    __syncthreads();
    for (int e = cs + threadIdx.x; e < ce; e += blockDim.x)
        atomicAdd(&h[row[e] >> COARSE_SHIFT], 1);
    __syncthreads();
    for (int b = threadIdx.x; b < MAXB; b += blockDim.x) {
        int c = h[b];
        base[b] = c ? atomicAdd(&cursor[b], c) : 0;
        h[b] = 0;
    }
    __syncthreads();
    for (int e = cs + threadIdx.x; e < ce; e += blockDim.x) {
        int d = row[e];
        int b = d >> COARSE_SHIFT;
        int off = atomicAdd(&h[b], 1);
        int pos = base[b] + off;
        stage[pos] = ((d & 1023) << 22) | col[e];
        stageVal[pos] = val[e];
    }
}

// ---------------- full per-row sort within coarse bucket (L2-resident) ----------------
// Emits row-sorted keys (bin) and global CSR rowStart[N+1].
__global__ void __launch_bounds__(256)
subsort(const int* __restrict__ coarseStart,
        const int* __restrict__ stage, const float* __restrict__ stageVal,
        int* __restrict__ bin, float* __restrict__ binVal,
        int* __restrict__ rowStart, int Bc, int N, int total) {
    __shared__ int h[1024];
    __shared__ int base[1024];
    __shared__ int sarr[256];
    int c = blockIdx.x;
    int s = coarseStart[c], e = coarseStart[c + 1];
    for (int i = threadIdx.x; i < 1024; i += 256) h[i] = 0;
    __syncthreads();
    for (int j = s + threadIdx.x; j < e; j += 256)
        atomicAdd(&h[(stage[j] >> 22) & 1023], 1);
    __syncthreads();
    int t = threadIdx.x;
    int l0 = h[4*t], l1 = h[4*t+1], l2 = h[4*t+2], l3 = h[4*t+3];
    int lsum = l0 + l1 + l2 + l3;
    sarr[t] = lsum;
    __syncthreads();
    for (int off = 1; off < 256; off <<= 1) {
        int v = (t >= off) ? sarr[t - off] : 0;
        __syncthreads();
        sarr[t] += v;
        __syncthreads();
    }
    int excl = sarr[t] - lsum;
    base[4*t] = excl; base[4*t+1] = excl + l0;
    base[4*t+2] = excl + l0 + l1; base[4*t+3] = excl + l0 + l1 + l2;
    __syncthreads();
    int rowBase = c << COARSE_SHIFT;
    for (int i = threadIdx.x; i < 1024; i += 256) {
        int gr = rowBase + i;
        if (gr < N) rowStart[gr] = s + base[i];
    }
    if (threadIdx.x == 0 && c == Bc - 1) rowStart[N] = total;
    for (int i = threadIdx.x; i < 1024; i += 256) h[i] = 0;
    __syncthreads();
    for (int j = s + threadIdx.x; j < e; j += 256) {
        int k = stage[j];
        int r = (k >> 22) & 1023;
        int pos = s + base[r] + atomicAdd(&h[r], 1);
        bin[pos] = k;
        if (binVal) binVal[pos] = stageVal[j];
    }
}

// ---------------- gathers ----------------
// One wave per dest row. lane = 16*q + l: q = edge slot (4 slots), l = float4 group.
// Row's edge keys loaded once, coalesced, into registers (lane e holds key of
// edge e); per-edge keys distributed by __shfl.
// CORRECTNESS INVARIANT: every __shfl executes with ALL 64 lanes active
// (ds_bpermute from an inactive lane is undefined). Main loop trip count is
// wave-uniform (cap>>3); epilogue entry (cap&7) is wave-uniform, shfls issue
// before the per-group predicate. Lanes >= deg hold myk=0 (valid row 0).

__device__ __forceinline__ void fma4(float4& acc, const float4 v, const float4 w) {
    acc.x += v.x * w.x; acc.y += v.y * w.y;
    acc.z += v.z * w.z; acc.w += v.w * w.w;
}

__global__ void __launch_bounds__(256)
ent_gather(const float* __restrict__ entCur,
           const float4* __restrict__ weight,
           const int* __restrict__ rowStart,
           const int* __restrict__ bin,
           float* __restrict__ entNew,
           float* __restrict__ entNorm,
           int NE) {
    __shared__ float4 wlds[15 * 16];
    for (int i = threadIdx.x; i < 15 * 16; i += blockDim.x) wlds[i] = weight[i];
    __syncthreads();
    int row = blockIdx.x * (blockDim.x >> 6) + (threadIdx.x >> 6);
    int lane = threadIdx.x & 63;
    int q = lane >> 4, l = lane & 15;
    if (row >= NE) return;
    int start = rowStart[row], end = rowStart[row + 1];
    int deg = end - start;
    int myk = (lane < deg) ? bin[start + lane] : 0;   // one coalesced 64-wide load
    int cap = deg < 64 ? deg : 64;
    int full = cap >> 3;                              // uniform trip count
    float4 acc = make_float4(0.f, 0.f, 0.f, 0.f);
    for (int t = 0; t < full; ++t) {
        int eA = q + (t << 3);
        int kA = __shfl(myk, eA, 64);
        int kB = __shfl(myk, eA + 4, 64);
        float4 vA = ((const float4*)(entCur + (long)(kA & 0x3FFFF) * CDIM))[l];
        float4 vB = ((const float4*)(entCur + (long)(kB & 0x3FFFF) * CDIM))[l];
        fma4(acc, vA, wlds[((kA >> 18) & 15) * 16 + l]);
        fma4(acc, vB, wlds[((kB >> 18) & 15) * 16 + l]);
    }
    if (cap & 7) {                                    // uniform entry
        int eA = q + (full << 3), eB = eA + 4;        // eA<=59, eB<=63: valid lanes
        int kA = __shfl(myk, eA, 64);
        int kB = __shfl(myk, eB, 64);
        if (eA < cap) {
            float4 v = ((const float4*)(entCur + (long)(kA & 0x3FFFF) * CDIM))[l];
            fma4(acc, v, wlds[((kA >> 18) & 15) * 16 + l]);
        }
        if (eB < cap) {
            float4 v = ((const float4*)(entCur + (long)(kB & 0x3FFFF) * CDIM))[l];
            fma4(acc, v, wlds[((kB >> 18) & 15) * 16 + l]);
        }
    }
    for (int j = start + 64 + q; j < end; j += 4) {   // rare overflow (deg > 64)
        int k = bin[j];
        float4 v = ((const float4*)(entCur + (long)(k & 0x3FFFF) * CDIM))[l];
        fma4(acc, v, wlds[((k >> 18) & 15) * 16 + l]);
    }
    #pragma unroll
    for (int off = 16; off < 64; off <<= 1) {
        acc.x += __shfl_xor(acc.x, off, 64);
        acc.y += __shfl_xor(acc.y, off, 64);
        acc.z += __shfl_xor(acc.z, off, 64);
        acc.w += __shfl_xor(acc.w, off, 64);
    }
    float inv = 1.0f / fmaxf((float)deg, 1.0f);
    float4 mean = make_float4(acc.x * inv, acc.y * inv, acc.z * inv, acc.w * inv);
    float q2 = mean.x * mean.x + mean.y * mean.y + mean.z * mean.z + mean.w * mean.w;
    #pragma unroll
    for (int off = 1; off < 16; off <<= 1) q2 += __shfl_xor(q2, off, 64);
    float n = fmaxf(sqrtf(q2), 1e-12f);
    float rn = 1.0f / n;
    if (q == 0) {
        ((float4*)(entNew + (long)row * CDIM))[l] =
            make_float4(mean.x * rn, mean.y * rn, mean.z * rn, mean.w * rn);
        if (l == 0) entNorm[row] = n;
    }
}

__global__ void __launch_bounds__(256)
node_gather(const float* __restrict__ nodeUold,
            const float* __restrict__ entCur,
            const float4* __restrict__ extraW,
            const int* __restrict__ rowStart,
            const int* __restrict__ bin,
            float* __restrict__ nodeUnew,
            float* __restrict__ resOut,
            int NN, int NU) {
    __shared__ float4 wlds[16 * 16];
    for (int i = threadIdx.x; i < 16 * 16; i += blockDim.x) wlds[i] = extraW[i];
    __syncthreads();
    int row = blockIdx.x * (blockDim.x >> 6) + (threadIdx.x >> 6);
    int lane = threadIdx.x & 63;
    int q = lane >> 4, l = lane & 15;
    if (row >= NN) return;
    int start = rowStart[row], end = rowStart[row + 1];
    int deg = end - start;
    int myk = (lane < deg) ? bin[start + lane] : 0;
    int cap = deg < 64 ? deg : 64;
    int full = cap >> 3;
    float4 acc = make_float4(0.f, 0.f, 0.f, 0.f);
    for (int t = 0; t < full; ++t) {
        int eA = q + (t << 3);
        int kA = __shfl(myk, eA, 64);
        int kB = __shfl(myk, eA + 4, 64);
        int sA = kA & 0x3FFFF, sB = kB & 0x3FFFF;
        const float* bA = (sA < NU) ? (nodeUold + (long)sA * CDIM)
                                    : (entCur + (long)(sA - NU) * CDIM);
        const float* bB = (sB < NU) ? (nodeUold + (long)sB * CDIM)
                                    : (entCur + (long)(sB - NU) * CDIM);
        float4 vA = ((const float4*)bA)[l];
        float4 vB = ((const float4*)bB)[l];
        fma4(acc, vA, wlds[((kA >> 18) & 15) * 16 + l]);
        fma4(acc, vB, wlds[((kB >> 18) & 15) * 16 + l]);
    }
    if (cap & 7) {
        int eA = q + (full << 3), eB = eA + 4;
        int kA = __shfl(myk, eA, 64);
        int kB = __shfl(myk, eB, 64);
        if (eA < cap) {
            int s = kA & 0x3FFFF;
            const float* b = (s < NU) ? (nodeUold + (long)s * CDIM)
                                      : (entCur + (long)(s - NU) * CDIM);
            fma4(acc, ((const float4*)b)[l], wlds[((kA >> 18) & 15) * 16 + l]);
        }
        if (eB < cap) {
            int s = kB & 0x3FFFF;
            const float* b = (s < NU) ? (nodeUold + (long)s * CDIM)
                                      : (entCur + (long)(s - NU) * CDIM);
            fma4(acc, ((const float4*)b)[l], wlds[((kB >> 18) & 15) * 16 + l]);
        }
    }
    for (int j = start + 64 + q; j < end; j += 4) {
        int k = bin[j];
        int s = k & 0x3FFFF;
        const float* b = (s < NU) ? (nodeUold + (long)s * CDIM)
                                  : (entCur + (long)(s - NU) * CDIM);
        float4 v = ((const float4*)b)[l];
        fma4(acc, v, wlds[((k >> 18) & 15) * 16 + l]);
    }
    #pragma unroll
    for (int off = 16; off < 64; off <<= 1) {
        acc.x += __shfl_xor(acc.x, off, 64);
        acc.y += __shfl_xor(acc.y, off, 64);
        acc.z += __shfl_xor(acc.z, off, 64);
        acc.w += __shfl_xor(acc.w, off, 64);
    }
    float inv = 1.0f / fmaxf((float)deg, 1.0f);
    float4 mean = make_float4(acc.x * inv, acc.y * inv, acc.z * inv, acc.w * inv);
    float q2 = mean.x * mean.x + mean.y * mean.y + mean.z * mean.z + mean.w * mean.w;
    #pragma unroll
    for (int off = 1; off < 16; off <<= 1) q2 += __shfl_xor(q2, off, 64);
    float rn = 1.0f / fmaxf(sqrtf(q2), 1e-12f);
    if (q == 0) {
        float4 o = make_float4(mean.x * rn, mean.y * rn, mean.z * rn, mean.w * rn);
        float4* resRow = (float4*)(resOut + (long)row * CDIM);
        float4 rv = resRow[l];
        resRow[l] = make_float4(rv.x + o.x, rv.y + o.y, rv.z + o.z, rv.w + o.w);
        if (row < NU) ((float4*)(nodeUnew + (long)row * CDIM))[l] = o;
    }
}

__global__ void __launch_bounds__(256)
user_gather(const float* __restrict__ entNew,
            const float* __restrict__ entNorm,
            const int* __restrict__ rowStart,
            const int* __restrict__ bin,
            const float* __restrict__ binVal,
            float* __restrict__ userRes,
            int NU) {
    int row = blockIdx.x * (blockDim.x >> 6) + (threadIdx.x >> 6);
    int lane = threadIdx.x & 63;
    int q = lane >> 4, l = lane & 15;
    if (row >= NU) return;
    int start = rowStart[row], end = rowStart[row + 1];
    int deg = end - start;
    int myk = 0; float myv = 0.f;
    if (lane < deg) { myk = bin[start + lane]; myv = binVal[start + lane]; }
    int cap = deg < 64 ? deg : 64;
    int full = cap >> 3;
    float4 acc = make_float4(0.f, 0.f, 0.f, 0.f);
    for (int t = 0; t < full; ++t) {
        int eA = q + (t << 3);
        int kA = __shfl(myk, eA, 64);
        int kB = __shfl(myk, eA + 4, 64);
        float vaA = __shfl(myv, eA, 64);
        float vaB = __shfl(myv, eA + 4, 64);
        int cA = kA & 0x3FFFFF, cB = kB & 0x3FFFFF;
        float fA = entNorm[cA] * vaA;
        float fB = entNorm[cB] * vaB;
        float4 vA = ((const float4*)(entNew + (long)cA * CDIM))[l];
        float4 vB = ((const float4*)(entNew + (long)cB * CDIM))[l];
        acc.x += vA.x * fA; acc.y += vA.y * fA;
        acc.z += vA.z * fA; acc.w += vA.w * fA;
        acc.x += vB.x * fB; acc.y += vB.y * fB;
        acc.z += vB.z * fB; acc.w += vB.w * fB;
    }
    if (cap & 7) {
        int eA = q + (full << 3), eB = eA + 4;
        int kA = __shfl(myk, eA, 64);
        int kB = __shfl(myk, eB, 64);
        float vaA = __shfl(myv, eA, 64);
        float vaB = __shfl(myv, eB, 64);
        if (eA < cap) {
            int col = kA & 0x3FFFFF;
            float f = entNorm[col] * vaA;
            float4 v = ((const float4*)(entNew + (long)col * CDIM))[l];
            acc.x += v.x * f; acc.y += v.y * f;
            acc.z += v.z * f; acc.w += v.w * f;
        }
        if (eB < cap) {
            int col = kB & 0x3FFFFF;
            float f = entNorm[col] * vaB;
            float4 v = ((const float4*)(entNew + (long)col * CDIM))[l];
            acc.x += v.x * f; acc.y += v.y * f;
            acc.z += v.z * f; acc.w += v.w * f;
        }
    }
    for (int j = start + 64 + q; j < end; j += 4) {
        int col = bin[j] & 0x3FFFFF;
        float f = entNorm[col] * binVal[j];
        float4 v = ((const float4*)(entNew + (long)col * CDIM))[l];
        acc.x += v.x * f; acc.y += v.y * f;
        acc.z += v.z * f; acc.w += v.w * f;
    }
    #pragma unroll
    for (int off = 16; off < 64; off <<= 1) {
        acc.x += __shfl_xor(acc.x, off, 64);
        acc.y += __shfl_xor(acc.y, off, 64);
        acc.z += __shfl_xor(acc.z, off, 64);
        acc.w += __shfl_xor(acc.w, off, 64);
    }
    float q2 = acc.x * acc.x + acc.y * acc.y + acc.z * acc.z + acc.w * acc.w;
    #pragma unroll
    for (int off = 1; off < 16; off <<= 1) q2 += __shfl_xor(q2, off, 64);
    float rn = 1.0f / fmaxf(sqrtf(q2), 1e-12f);
    if (q == 0) {
        float4* resRow = (float4*)(userRes + (long)row * CDIM);
        float4 rv = resRow[l];
        resRow[l] = make_float4(rv.x + acc.x * rn, rv.y + acc.y * rn,
                                rv.z + acc.z * rn, rv.w + acc.w * rn);
    }
}

__global__ void fill_debug(float* __restrict__ out, long n, float val) {
    long i = (long)blockIdx.x * blockDim.x + threadIdx.x;
    if (i < n) out[i] = val;
}

extern "C" void kernel_launch(void* const* d_in, const int* in_sizes, int n_in,
                              void* d_out, int out_size, void* d_ws, size_t ws_size,
                              hipStream_t stream) {
    const float* user_emb = (const float*)d_in[0];
    const float* ent_emb  = (const float*)d_in[1];
    const float* weight   = (const float*)d_in[2];
    const float* extraW   = (const float*)d_in[3];
    const float* imVal    = (const float*)d_in[4];
    const int*   eidx     = (const int*)d_in[5];
    const int*   etype    = (const int*)d_in[6];
    const int*   xidx     = (const int*)d_in[7];
    const int*   xtype    = (const int*)d_in[8];
    const int*   imRow    = (const int*)d_in[9];
    const int*   imCol    = (const int*)d_in[10];

    const int NU  = in_sizes[0] / CDIM;
    const int NE  = in_sizes[1] / CDIM;
    const int NN  = NU + NE;
    const int E   = in_sizes[5] / 2;
    const int E2  = in_sizes[7] / 2;
    const int NNZ = in_sizes[4];
    const long nuC = (long)NU * CDIM, neC = (long)NE * CDIM, nnC = (long)NN * CDIM;

    const int BcE = (NE + 1023) >> 10, BcN = (NN + 1023) >> 10, BcU = (NU + 1023) >> 10;

    float* out = (float*)d_out;
    float* outUserRes = out;            // [0 : nuC]
    float* entOut     = out + nuC;      // [nuC : nnC] ping-pong; final hop lands here
    float* outNodeRes = out + nnC;      // [nnC : 2nnC]

    // ---- workspace layout ----
    size_t required = (size_t)(neC + 2 * nuC) * 4          // entA, nodeU_A, nodeU_B
                    + (size_t)NE * 4                        // entNorm
                    + (size_t)(E + E2 + NNZ) * 4 * 2        // stage + bin keys
                    + (size_t)NNZ * 4 * 2                   // stageVal + binVal
                    + (size_t)(3 * MAXB) * 4                // coarse counts
                    + (size_t)(3 * (MAXB + 1)) * 4          // coarse starts
                    + (size_t)(3 * MAXB) * 4                // cursors
                    + (size_t)(NE + NN + NU + 3) * 4;       // rowStart CSR arrays
    if (ws_size < required) {
        long total = 2 * nnC;
        fill_debug<<<(total + 255) / 256, 256, 0, stream>>>(out, total, (float)(ws_size >> 20));
        return;
    }

    char* w = (char*)d_ws;
    float* entA     = (float*)w; w += (size_t)neC * 4;
    float* nodeU_A  = (float*)w; w += (size_t)nuC * 4;
    float* nodeU_B  = (float*)w; w += (size_t)nuC * 4;
    float* entNorm  = (float*)w; w += (size_t)NE * 4;
    int* stageEnt   = (int*)w;   w += (size_t)E * 4;
    int* stageNode  = (int*)w;   w += (size_t)E2 * 4;
    int* stageU     = (int*)w;   w += (size_t)NNZ * 4;
    float* stageUv  = (float*)w; w += (size_t)NNZ * 4;
    int* binEnt     = (int*)w;   w += (size_t)E * 4;
    int* binNode    = (int*)w;   w += (size_t)E2 * 4;
    int* binU       = (int*)w;   w += (size_t)NNZ * 4;
    float* binUv    = (float*)w; w += (size_t)NNZ * 4;
    int* cntC       = (int*)w;   w += (size_t)(3 * MAXB) * 4;
    int* startE     = (int*)w;   w += (size_t)(MAXB + 1) * 4;
    int* startN     = (int*)w;   w += (size_t)(MAXB + 1) * 4;
    int* startU     = (int*)w;   w += (size_t)(MAXB + 1) * 4;
    int* curE       = (int*)w;   w += (size_t)MAXB * 4;
    int* curN       = (int*)w;   w += (size_t)MAXB * 4;
    int* curU       = (int*)w;   w += (size_t)MAXB * 4;
    int* rowSE      = (int*)w;   w += (size_t)(NE + 1) * 4;
    int* rowSN      = (int*)w;   w += (size_t)(NN + 1) * 4;
    int* rowSU      = (int*)w;   w += (size_t)(NU + 1) * 4;

    const int* head = eidx;  const int* tail = eidx + E;
    const int* eh   = xidx;  const int* et   = xidx + E2;

    hipMemsetAsync(cntC, 0, (size_t)(3 * MAXB) * 4, stream);

    long initN4 = (nuC > neC ? nuC : neC) / 4;
    init_kernel<<<(initN4 + 255) / 256, 256, 0, stream>>>(
        (const float4*)user_emb, (const float4*)ent_emb,
        (float4*)outUserRes, (float4*)outNodeRes, nuC / 4, neC / 4);

    // ---- build: hist -> scan -> coarse bin -> per-row subsort (CSR) ----
    hist_coarse<<<256, 256, 0, stream>>>(head,  E,   cntC,            BcE);
    hist_coarse<<<256, 256, 0, stream>>>(eh,    E2,  cntC + MAXB,     BcN);
    hist_coarse<<<256, 256, 0, stream>>>(imRow, NNZ, cntC + 2 * MAXB, BcU);

    scan_small<<<1, 256, 0, stream>>>(cntC,            startE, curE, BcE);
    scan_small<<<1, 256, 0, stream>>>(cntC + MAXB,     startN, curN, BcN);
    scan_small<<<1, 256, 0, stream>>>(cntC + 2 * MAXB, startU, curU, BcU);

    bin_pairs<<<(E  + CHUNK - 1) / CHUNK, 256, 0, stream>>>(head, tail, etype, -1, E,  curE, stageEnt);
    bin_pairs<<<(E2 + CHUNK - 1) / CHUNK, 256, 0, stream>>>(eh,   et,   xtype,  0, E2, curN, stageNode);
    bin_user <<<(NNZ + CHUNK - 1) / CHUNK, 256, 0, stream>>>(imRow, imCol, imVal, NNZ, curU, stageU, stageUv);

    subsort<<<BcE, 256, 0, stream>>>(startE, stageEnt,  nullptr, binEnt,  nullptr, rowSE, BcE, NE, E);
    subsort<<<BcN, 256, 0, stream>>>(startN, stageNode, nullptr, binNode, nullptr, rowSN, BcN, NN, E2);
    subsort<<<BcU, 256, 0, stream>>>(startU, stageU,    stageUv, binU,    binUv,   rowSU, BcU, NU, NNZ);

    // ---- 3 hops (register-key gathers, wave-uniform shfl loops) ----
    const float* entCurP  = ent_emb;   float* entNewP  = entOut;
    const float* nodeOldP = user_emb;  float* nodeNewP = nodeU_A;

    for (int hop = 0; hop < 3; ++hop) {
        ent_gather<<<(NE + 3) / 4, 256, 0, stream>>>(
            entCurP, (const float4*)weight, rowSE, binEnt, entNewP, entNorm, NE);
        node_gather<<<(NN + 3) / 4, 256, 0, stream>>>(
            nodeOldP, entCurP, (const float4*)extraW, rowSN, binNode,
            nodeNewP, outNodeRes, NN, NU);
        user_gather<<<(NU + 3) / 4, 256, 0, stream>>>(
            entNewP, entNorm, rowSU, binU, binUv, outUserRes, NU);

        if (hop == 0) {
            entCurP = entOut;  entNewP = entA;
            nodeOldP = nodeU_A; nodeNewP = nodeU_B;
        } else if (hop == 1) {
            entCurP = entA;    entNewP = entOut;
            nodeOldP = nodeU_B; nodeNewP = nodeU_A;
        }
    }
}